// Round 5
// baseline (311.704 us; speedup 1.0000x reference)
//
#include <hip/hip_runtime.h>
#include <math.h>

#define VOCAB   5000
#define T_CTC   512
#define S_TGT   128
#define BATCH   16
#define ALPHA_W 0.2f
#define CONF    0.9f            // 1 - smoothing
#define OFFV    (0.1f / 4999.0f)
#define CSTR    132             // compact row stride (floats): 129 used, 16B-aligned
#define ATT_N   (BATCH * S_TGT) // 2048 attention rows
#define WS_OFF  4096            // compact buffer starts at ws + 4096 floats (16 KB)
#define TCH     16              // t-rows per gather chunk
#define GATHER_BLKS (BATCH * (T_CTC / TCH))   // 512
#define CHAIN_BASE  GATHER_BLKS               // blocks 512..527: chain
#define ATT_BASE    (CHAIN_BASE + BATCH)      // blocks 528..2575: att rows
#define TOTAL_BLKS  (ATT_BASE + ATT_N)        // 2576
#define FLAG_IDX    (ATT_N + BATCH)           // 16 ints at ws float-slot 2064
#define FLAG_BYTE_OFF (FLAG_IDX * 4)          // 8256

// ---------------------------------------------------------------------------
// DPP wave_shr:1 on a double: lane k receives lane k-1's value, lane 0 gets 0.
// ---------------------------------------------------------------------------
__device__ __forceinline__ double dpp_shr1(double x)
{
    const int lo  = __double2loint(x);
    const int hi  = __double2hiint(x);
    const int slo = __builtin_amdgcn_update_dpp(0, lo, 0x138, 0xF, 0xF, true);
    const int shi = __builtin_amdgcn_update_dpp(0, hi, 0x138, 0xF, 0xF, true);
    return __hiloint2double(shi, slo);
}

// ---------------------------------------------------------------------------
// Chain helpers: 16-step register-prefetch + pure-VALU serial chain.
// Buffers must stay in VGPRs — kernel carries __launch_bounds__(256, 2)
// (round 3 measured the default heuristic at 64 VGPR -> scratch -> 103 us).
// ---------------------------------------------------------------------------
__device__ __forceinline__ void prefetch16(const float* __restrict__ cbuf,
                                           int base, int k, float2* E, float* Z)
{
    #pragma unroll
    for (int i = 0; i < 16; ++i) {
        int t = base + i;
        t = (t < T_CTC) ? t : (T_CTC - 1);          // clamp (clamped steps guarded out)
        const float* row = cbuf + (size_t)t * CSTR;
        E[i] = *reinterpret_cast<const float2*>(row + 2 * k);  // 512B/wave, coalesced
        Z[i] = row[S_TGT];                                      // blank col broadcast
    }
}

template<bool TAIL>
__device__ __forceinline__ void run16(const float2* E, const float* Z, int base,
                                      double& b0, double& b1, double& b2,
                                      double& b3, double& b4, double& M,
                                      const double g1, const double g3)
{
    #pragma unroll
    for (int i = 0; i < 16; ++i) {
        if (TAIL && (base + i >= T_CTC)) return;     // uniform scalar branch
        const float  e0 = Z[i];
        const double X1 = (double)__expf(E[i].x - e0);   // off-chain
        const double X3 = (double)__expf(E[i].y - e0);
        const double p3 = dpp_shr1(b3);                  // lane k-1's state 4k-1
        const double n0 = b0 + p3;
        const double n1 = (b1 + b0 + g1 * p3) * X1;
        const double n2 = b2 + b1;
        const double n3 = (b3 + b2 + g3 * b1) * X3;
        const double n4 = b4 + b3;
        b0 = n0; b1 = n1; b2 = n2; b3 = n3; b4 = n4;
        M += (double)e0;
    }
}

// ---------------------------------------------------------------------------
// Fused kernel: gather (blocks 0..511, first in dispatch order) -> per-batch
// ready flags; chain (blocks 512..527) spins on its batch's flag (==32) with
// the round-3-proven fence/atomic visibility pattern; att rows (528..2575)
// stream throughout, overlapping both latency-bound phases.
// Deadlock-free: only 16 blocks wait; >=512 blocks co-resident; waiters'
// producers are first in dispatch order.
// ---------------------------------------------------------------------------
__global__ __launch_bounds__(256, 2)
void fused_kernel(const float* __restrict__ ctc, const float* __restrict__ att,
                  const int* __restrict__ tgt, float* __restrict__ ws)
{
    const int bid = blockIdx.x;
    const int tid = threadIdx.x;

    if (bid < GATHER_BLKS) {
        // ---- scattered gather chunk: (batch b, 16 t-rows), 8 loads in flight ----
        const int b = bid >> 5;
        const int c = bid & 31;

        __shared__ int tg[S_TGT];
        if (tid < S_TGT) tg[tid] = tgt[b * S_TGT + tid];
        __syncthreads();

        const float* lp   = ctc + ((size_t)b * T_CTC + (size_t)c * TCH) * VOCAB;
        float*       cbuf = ws + WS_OFF + ((size_t)b * T_CTC + (size_t)c * TCH) * CSTR;

        for (int v = tid; v < 258; v += 256) {
            const int tt0 = (v < 129) ? 0 : 1;
            const int idx = (v < 129) ? v : v - 129;
            const int col = (idx < S_TGT) ? tg[idx] : 0;   // 128 -> blank
            float val[TCH / 2];
            #pragma unroll
            for (int p = 0; p < TCH / 2; ++p)
                val[p] = lp[(size_t)(2 * p + tt0) * VOCAB + col];
            #pragma unroll
            for (int p = 0; p < TCH / 2; ++p)
                cbuf[(size_t)(2 * p + tt0) * CSTR + idx] = val[p];
        }

        __syncthreads();                                  // all chunk stores issued
        if (tid == 0) {
            __threadfence();                              // release (round-3-proven)
            atomicAdd((int*)ws + FLAG_IDX + b, 1);        // device-scope
        }
        return;
    }

    if (bid >= ATT_BASE) {
        // ---- label-smoothing att row ----
        const int rr = bid - ATT_BASE;                    // 0..2047
        const float* row = att + (size_t)rr * VOCAB;

        float tl = 0.0f;
        if (tid == 0) tl = row[tgt[rr]];                  // issue early, off-path

        const float4* row4 = (const float4*)row;          // 1250 float4 exact
        float sum = 0.0f;
        for (int i = tid; i < VOCAB / 4; i += 256) {
            float4 v = row4[i];
            sum += v.x + v.y + v.z + v.w;
        }
        #pragma unroll
        for (int off = 32; off > 0; off >>= 1)
            sum += __shfl_down(sum, off, 64);

        __shared__ float wsum[4];
        if ((tid & 63) == 0) wsum[tid >> 6] = sum;
        __syncthreads();
        if (tid == 0) {
            const float rs = wsum[0] + wsum[1] + wsum[2] + wsum[3];
            ws[rr] = -(CONF * tl + OFFV * (rs - tl));     // per-row partial
        }
        return;
    }

    // ---- CTC chain (one wave per batch) ----
    if (tid >= 64) return;
    const int b = bid - CHAIN_BASE;
    const int k = tid;                                    // lane owns states 4k..4k+3
    const int*   tg   = tgt + b * S_TGT;
    const float* cbuf = ws + WS_OFF + (size_t)b * T_CTC * CSTR;

    // input-only prep (no cbuf dependence) before the spin
    const int t1 = tg[2 * k];
    const int t3 = tg[2 * k + 1];
    const int tp = (k > 0) ? tg[2 * k - 1] : 0;
    const double g1 = ((k > 0) && (t1 != 0) && (t1 != tp)) ? 1.0 : 0.0;
    const double g3 = ((t3 != 0) && (t3 != t1)) ? 1.0 : 0.0;

    // spin until this batch's 32 gather chunks are done (acquire)
    {
        int* flag = (int*)ws + FLAG_IDX + b;
        int r;
        do {
            r = __hip_atomic_load(flag, __ATOMIC_ACQUIRE, __HIP_MEMORY_SCOPE_AGENT);
            if (r != 32) __builtin_amdgcn_s_sleep(8);
        } while (r != 32);
    }

    const float e00 = cbuf[S_TGT];                        // t=0 blank
    double M  = (double)e00;
    double b0 = (k == 0) ? 1.0 : 0.0;
    double b1 = (k == 0) ? (double)__expf(cbuf[0] - e00) : 0.0;
    double b2 = 0.0, b3 = 0.0, b4 = 0.0;

    float2 EA[16], EB[16];
    float  ZA[16], ZB[16];

    prefetch16(cbuf, 1, k, EA, ZA);
    for (int h2 = 0; h2 < 16; ++h2) {                     // 2 x 16 steps per iter
        const int base0 = 1 + 32 * h2;
        prefetch16(cbuf, base0 + 16, k, EB, ZB);          // in flight during EA chain
        run16<false>(EA, ZA, base0, b0, b1, b2, b3, b4, M, g1, g3);
        if (h2 < 15) {
            prefetch16(cbuf, base0 + 32, k, EA, ZA);      // in flight during EB chain
            run16<false>(EB, ZB, base0 + 16, b0, b1, b2, b3, b4, M, g1, g3);
        } else {
            run16<true>(EB, ZB, base0 + 16, b0, b1, b2, b3, b4, M, g1, g3);
        }
    }

    if (k == 63) {
        const double bsum = b3 + b4;                      // states 255, 256
        const double ll   = M + log(bsum);                // bsum==0 -> -inf
        float loss_b = (float)(-ll);
        if (!(loss_b <= 1e20f)) loss_b = 0.0f;            // zero_infinity
        ws[ATT_N + b] = loss_b;                           // per-batch slot
    }
}

// ---------------------------------------------------------------------------
// Final reduction of 2048 att partials + 16 ctc losses (kept separate: the
// fused last-block ticket measured +44 us in round 3).
// ---------------------------------------------------------------------------
__global__ __launch_bounds__(256)
void combine_kernel(const float* __restrict__ ws, float* __restrict__ out)
{
    const int tid = threadIdx.x;
    float s_att = 0.0f;
    for (int i = tid; i < ATT_N; i += 256) s_att += ws[i];
    float s_ctc = (tid < BATCH) ? ws[ATT_N + tid] : 0.0f;

    #pragma unroll
    for (int off = 32; off > 0; off >>= 1) {
        s_att += __shfl_down(s_att, off, 64);
        s_ctc += __shfl_down(s_ctc, off, 64);
    }
    __shared__ float wa[4], wc[4];
    if ((tid & 63) == 0) { wa[tid >> 6] = s_att; wc[tid >> 6] = s_ctc; }
    __syncthreads();
    if (tid == 0) {
        const float inv = 1.0f / (float)ATT_N;            // both sums / 2048
        const float a = (wa[0] + wa[1] + wa[2] + wa[3]) * inv;
        const float c = (wc[0] + wc[1] + wc[2] + wc[3]) * inv;
        out[0] = ALPHA_W * a + (1.0f - ALPHA_W) * c;
    }
}

extern "C" void kernel_launch(void* const* d_in, const int* in_sizes, int n_in,
                              void* d_out, int out_size, void* d_ws, size_t ws_size,
                              hipStream_t stream)
{
    const float* att = (const float*)d_in[0];
    const float* ctc = (const float*)d_in[1];
    const int*   tgt = (const int*)d_in[2];
    float* out = (float*)d_out;
    float* ws  = (float*)d_ws;

    // zero the 16 per-batch ready flags (ws is poison-filled every iteration)
    hipMemsetAsync((char*)ws + FLAG_BYTE_OFF, 0, BATCH * sizeof(int), stream);
    fused_kernel<<<TOTAL_BLKS, 256, 0, stream>>>(ctc, att, tgt, ws);
    combine_kernel<<<1, 256, 0, stream>>>(ws, out);
}